// Round 1
// baseline (5788.185 us; speedup 1.0000x reference)
//
#include <hip/hip_runtime.h>
#include <stdint.h>

#define NPTS (1u << 21)   // 4*512*1024
#define KC 256
#define KM_ITERS 10
#define CHUNK 4096
#define NCHUNK (NPTS / CHUNK)   // 512

// -------- threefry2x32 (JAX PRNG) with explicit key, both output words ------
__device__ __forceinline__ uint32_t rotl32(uint32_t v, uint32_t s) {
  return (v << s) | (v >> (32u - s));
}

__device__ void threefry2x32_key(uint32_t k0, uint32_t k1,
                                 uint32_t c0, uint32_t c1,
                                 uint32_t* o0, uint32_t* o1) {
  uint32_t ks[3] = {k0, k1, k0 ^ k1 ^ 0x1BD11BDAu};
  uint32_t x0 = c0 + ks[0];
  uint32_t x1 = c1 + ks[1];
  const uint32_t rotA[4] = {13u, 15u, 26u, 6u};
  const uint32_t rotB[4] = {17u, 29u, 16u, 24u};
  #pragma unroll
  for (int i = 0; i < 5; ++i) {
    const uint32_t* rot = ((i & 1) == 0) ? rotA : rotB;
    #pragma unroll
    for (int r = 0; r < 4; ++r) {
      x0 += x1;
      x1 = rotl32(x1, rot[r]);
      x1 ^= x0;
    }
    x0 += ks[(i + 1) % 3];
    x1 += ks[(i + 2) % 3] + (uint32_t)(i + 1);
  }
  *o0 = x0;
  *o1 = x1;
}

// init: centers0 = x[randint(key(42),(256,),0,N)]  [R14/R16-validated: exact]
__global__ void km_init(const float* __restrict__ x, float* __restrict__ centers) {
  int j = threadIdx.x;  // 256 threads, 1 block
  uint32_t s0, s1;
  threefry2x32_key(0u, 42u, 0u, 1u, &s0, &s1);      // k2 = split(key(42))[1]
  uint32_t b0, b1;
  threefry2x32_key(s0, s1, 0u, (uint32_t)j, &b0, &b1);
  uint32_t idx = (b0 ^ b1) & (NPTS - 1u);
  centers[j] = x[idx];
}

// sort centers ascending (bitonic, value+orig index); rep[j] = min orig index
// among slots with equal value (exact-duplicate tie groups).
__global__ __launch_bounds__(256) void km_sort_centers(
    const float* __restrict__ centers, float* __restrict__ sortedC,
    uint32_t* __restrict__ rep) {
  __shared__ float v[KC];
  __shared__ int idx[KC];
  __shared__ uint32_t r[KC];
  const int t = threadIdx.x;
  v[t] = centers[t];
  idx[t] = t;
  __syncthreads();
  for (int size = 2; size <= KC; size <<= 1) {
    for (int stride = size >> 1; stride > 0; stride >>= 1) {
      int partner = t ^ stride;
      if (partner > t) {
        bool ascending = ((t & size) == 0);
        float va = v[t], vb = v[partner];
        int ia = idx[t], ib = idx[partner];
        bool doswap = ascending ? (va > vb) : (va < vb);
        if (doswap) { v[t] = vb; v[partner] = va; idx[t] = ib; idx[partner] = ia; }
      }
      __syncthreads();
    }
  }
  if (t == 0) {   // run-min of orig indices over equal-value groups (2 passes)
    float cv = v[0];
    uint32_t cur = (uint32_t)idx[0];
    r[0] = cur;
    for (int j = 1; j < KC; ++j) {
      if (v[j] == cv) { uint32_t ij = (uint32_t)idx[j]; cur = (ij < cur) ? ij : cur; }
      else { cv = v[j]; cur = (uint32_t)idx[j]; }
      r[j] = cur;
    }
    float nv = v[KC - 1];
    uint32_t nc = r[KC - 1];
    for (int j = KC - 2; j >= 0; --j) {
      if (v[j] == nv) { nc = (r[j] < nc) ? r[j] : nc; r[j] = nc; }
      else { nv = v[j]; nc = r[j]; }
    }
  }
  __syncthreads();
  sortedC[t] = v[t];
  rep[t] = r[t];
}

// exact-argmin via sorted binary search: upper-bound (count of <= x, capped
// 255), then 2-candidate f32 compare (same |x-c| ops as reference), ties ->
// min rep (first-original-index semantics). Exact dups handled by rep[].
__device__ __forceinline__ uint32_t bs_label(float x, const float* sC,
                                             const uint32_t* rp) {
  int pos = 0;
  #pragma unroll
  for (int d = 128; d >= 1; d >>= 1)
    if (sC[pos + d - 1] <= x) pos += d;
  if (pos == 0) return rp[0];
  float cl = sC[pos - 1], cr = sC[pos & 255];   // pos<=255 always; &255 for safety
  float dl = fabsf(x - cl), dr = fabsf(x - cr);
  if (dl < dr) return rp[pos - 1];
  if (dr < dl) return rp[pos];
  uint32_t a = rp[pos - 1], b = rp[pos];
  return a < b ? a : b;
}

// assign + per-chunk histogram via binary search (R23: replaces 256-sweep).
__global__ __launch_bounds__(256) void km_assign_hist(
    const float* __restrict__ x, const float* __restrict__ sortedC,
    const uint32_t* __restrict__ rep, uint32_t* __restrict__ hist) {
  __shared__ float sC[KC];
  __shared__ uint32_t rp[KC];
  __shared__ uint32_t sH[KC];
  const int t = threadIdx.x, b = blockIdx.x;
  sC[t] = sortedC[t];
  rp[t] = rep[t];
  sH[t] = 0u;
  __syncthreads();

  #pragma unroll
  for (int q = 0; q < 4; ++q) {
    const int i4 = b * (CHUNK / 4) + q * 256 + t;  // float4 index
    float4 xv = reinterpret_cast<const float4*>(x)[i4];
    uint32_t l0 = bs_label(xv.x, sC, rp);
    uint32_t l1 = bs_label(xv.y, sC, rp);
    uint32_t l2 = bs_label(xv.z, sC, rp);
    uint32_t l3 = bs_label(xv.w, sC, rp);
    atomicAdd(&sH[l0], 1u);
    atomicAdd(&sH[l1], 1u);
    atomicAdd(&sH[l2], 1u);
    atomicAdd(&sH[l3], 1u);
  }
  __syncthreads();
  hist[b * KC + t] = sH[t];
}

// parallel per-cluster exclusive scan over chunks (Hillis-Steele, exact ints).
__global__ __launch_bounds__(512) void km_scan_chunks(
    uint32_t* __restrict__ hist, uint32_t* __restrict__ clusterStart) {
  __shared__ uint32_t s[NCHUNK];
  const int k = blockIdx.x, t = threadIdx.x;
  uint32_t v = hist[t * KC + k];
  s[t] = v;
  __syncthreads();
  #pragma unroll
  for (int d = 1; d < NCHUNK; d <<= 1) {
    uint32_t u = (t >= d) ? s[t - d] : 0u;
    __syncthreads();
    s[t] += u;
    __syncthreads();
  }
  hist[t * KC + k] = s[t] - v;            // exclusive within cluster
  if (t == NCHUNK - 1) clusterStart[k] = s[t];  // total (temp)
}

// serial exclusive scan over the 256 cluster totals -> clusterStart[0..256]
__global__ void km_scan_clusters(uint32_t* __restrict__ clusterStart) {
  if (threadIdx.x != 0) return;
  uint32_t acc = 0;
  for (int j = 0; j < KC; ++j) {
    uint32_t t = clusterStart[j];
    clusterStart[j] = acc;
    acc += t;
  }
  clusterStart[KC] = acc;  // == NPTS
}

// stable scatter into sorted_x (= d_out used as scratch); labels via bs.
__global__ __launch_bounds__(256) void km_scatter(
    const float* __restrict__ x, const float* __restrict__ sortedC,
    const uint32_t* __restrict__ rep,
    const uint32_t* __restrict__ hist, const uint32_t* __restrict__ clusterStart,
    float* __restrict__ sorted_x) {
  __shared__ float sC[KC];
  __shared__ uint32_t rp[KC];
  __shared__ uint32_t run[KC];
  __shared__ uint32_t cntw[4][KC];
  __shared__ uint32_t basew[4][KC];
  const int t = threadIdx.x, b = blockIdx.x;
  const int w = t >> 6, lane = t & 63;
  sC[t] = sortedC[t];
  rp[t] = rep[t];
  run[t] = hist[b * KC + t] + clusterStart[t];
  __syncthreads();

  for (int r = 0; r < CHUNK / 256; ++r) {      // 16 rounds of 256 elements
    const int i = b * CHUNK + r * 256 + t;
    const float xv = x[i];
    uint32_t lab = bs_label(xv, sC, rp);
    unsigned long long m = ~0ULL;
    #pragma unroll
    for (int bit = 0; bit < 8; ++bit) {
      unsigned long long vote = __ballot((lab >> bit) & 1u);
      m &= ((lab >> bit) & 1u) ? vote : ~vote;
    }
    uint32_t rank = (uint32_t)__popcll(m & ((1ULL << lane) - 1ULL));
    uint32_t wcnt = (uint32_t)__popcll(m);
    cntw[0][t] = 0u; cntw[1][t] = 0u; cntw[2][t] = 0u; cntw[3][t] = 0u;
    __syncthreads();
    if (rank == 0) cntw[w][lab] = wcnt;
    __syncthreads();
    {
      uint32_t c0 = cntw[0][t], c1 = cntw[1][t], c2 = cntw[2][t], c3 = cntw[3][t];
      uint32_t base = run[t];
      basew[0][t] = base;
      basew[1][t] = base + c0;
      basew[2][t] = base + c0 + c1;
      basew[3][t] = base + c0 + c1 + c2;
      run[t] = base + c0 + c1 + c2 + c3;
    }
    __syncthreads();
    sorted_x[basew[w][lab] + rank] = xv;
  }
}

// ---- fold v3: direct-global register pipeline, no LDS, no syncs ------------
// Three 64-float register groups (16 float4 each) rotating at distance 3:
// the chain folds group t while groups t+1, t+2 are in flight (>=512 chain
// cycles of latency cover vs ~200-600 cy L2/L3). All lanes compute the same
// fold redundantly (same addresses -> broadcast coalesced); lane 0 stores.
// Addresses clamped to NPTS-4 so over-prefetch past the last cluster never
// faults; clamp never corrupts a group that is actually folded (valid groups
// satisfy s0 + 64g + 64 <= s1 <= NPTS). Fold order is bitwise-identical to
// the validated sequential left-fold (index order, .x.y.z.w within float4).
#define LDG4(v, g, j) { \
  uint32_t o_ = s0 + (((uint32_t)(g)) << 6) + ((uint32_t)(j) << 2); \
  o_ = (o_ > (NPTS - 4u)) ? (NPTS - 4u) : o_; \
  (v) = *reinterpret_cast<const float4*>(sx + o_); }

#define LOADG64(P, g) \
  LDG4(P##0, g, 0) LDG4(P##1, g, 1) LDG4(P##2, g, 2) LDG4(P##3, g, 3) \
  LDG4(P##4, g, 4) LDG4(P##5, g, 5) LDG4(P##6, g, 6) LDG4(P##7, g, 7) \
  LDG4(P##8, g, 8) LDG4(P##9, g, 9) LDG4(P##10, g, 10) LDG4(P##11, g, 11) \
  LDG4(P##12, g, 12) LDG4(P##13, g, 13) LDG4(P##14, g, 14) LDG4(P##15, g, 15)

#define F4(q) s += (q).x; s += (q).y; s += (q).z; s += (q).w;

#define FOLDG64(P) \
  F4(P##0) F4(P##1) F4(P##2) F4(P##3) F4(P##4) F4(P##5) F4(P##6) F4(P##7) \
  F4(P##8) F4(P##9) F4(P##10) F4(P##11) F4(P##12) F4(P##13) F4(P##14) F4(P##15)

__global__ __launch_bounds__(64, 1) void km_fold_update(
    const float* __restrict__ sorted_x, const uint32_t* __restrict__ clusterStart,
    float* __restrict__ centers) {
  const int k = blockIdx.x;
  const uint32_t s0 = clusterStart[k], s1 = clusterStart[k + 1];
  const uint32_t cnt = s1 - s0;
  const float* sx = sorted_x;
  const uint32_t nfull = cnt >> 6;   // number of full 64-float groups

  float s = 0.0f;
  float4 A0, A1, A2, A3, A4, A5, A6, A7, A8, A9, A10, A11, A12, A13, A14, A15;
  float4 B0, B1, B2, B3, B4, B5, B6, B7, B8, B9, B10, B11, B12, B13, B14, B15;
  float4 C0, C1, C2, C3, C4, C5, C6, C7, C8, C9, C10, C11, C12, C13, C14, C15;

  LOADG64(A, 0u)
  LOADG64(B, 1u)
  LOADG64(C, 2u)

  uint32_t t = 0u;
  while (t + 3u <= nfull) {
    FOLDG64(A) LOADG64(A, t + 3u)
    FOLDG64(B) LOADG64(B, t + 4u)
    FOLDG64(C) LOADG64(C, t + 5u)
    t += 3u;
  }
  if (t < nfull) { FOLDG64(A) }
  if (t + 1u < nfull) { FOLDG64(B) }

  // tail: remaining cnt & 63 elements, in order (scalar, bounds-exact)
  for (uint32_t j = nfull << 6; j < cnt; ++j) s += sx[s0 + j];

  if (threadIdx.x == 0 && cnt > 0u) centers[k] = s / (float)cnt;  // else keep old
}

// final assign + gather via binary search: out = centers[labels]
__global__ __launch_bounds__(256) void km_final(
    const float* __restrict__ x, const float* __restrict__ centers,
    const float* __restrict__ sortedC, const uint32_t* __restrict__ rep,
    float* __restrict__ out) {
  __shared__ float sC[KC];
  __shared__ uint32_t rp[KC];
  __shared__ float sCtr[KC];
  const int t = threadIdx.x;
  sC[t] = sortedC[t];
  rp[t] = rep[t];
  sCtr[t] = centers[t];
  __syncthreads();

  const int nv = (int)(NPTS / 4u);
  for (int i = blockIdx.x * blockDim.x + t; i < nv; i += gridDim.x * blockDim.x) {
    float4 xv = reinterpret_cast<const float4*>(x)[i];
    float4 o;
    o.x = sCtr[bs_label(xv.x, sC, rp)];
    o.y = sCtr[bs_label(xv.y, sC, rp)];
    o.z = sCtr[bs_label(xv.z, sC, rp)];
    o.w = sCtr[bs_label(xv.w, sC, rp)];
    reinterpret_cast<float4*>(out)[i] = o;
  }
}

extern "C" void kernel_launch(void* const* d_in, const int* in_sizes, int n_in,
                              void* d_out, int out_size, void* d_ws, size_t ws_size,
                              hipStream_t stream) {
  const float* x = (const float*)d_in[0];
  float* out = (float*)d_out;

  // ws layout (~520 KB):
  //   [0,1K)       centers f32[256]
  //   [1K,2.1K)    clusterStart u32[257]
  //   [2.5K,3.5K)  sortedC f32[256]
  //   [3.5K,4.5K)  rep u32[256]
  //   [8K,520K)    hist u32[512][256]
  // sorted_x (8 MB) lives in d_out — dead after fold, overwritten by km_final.
  uint8_t* ws = (uint8_t*)d_ws;
  float* centers = (float*)(ws + 0);
  uint32_t* clusterStart = (uint32_t*)(ws + 1024);
  float* sortedC = (float*)(ws + 2560);
  uint32_t* rep = (uint32_t*)(ws + 3584);
  uint32_t* hist = (uint32_t*)(ws + 8192);
  float* sorted_x = (float*)d_out;

  km_init<<<1, KC, 0, stream>>>(x, centers);
  for (int it = 0; it < KM_ITERS; ++it) {
    km_sort_centers<<<1, KC, 0, stream>>>(centers, sortedC, rep);
    km_assign_hist<<<NCHUNK, 256, 0, stream>>>(x, sortedC, rep, hist);
    km_scan_chunks<<<KC, NCHUNK, 0, stream>>>(hist, clusterStart);
    km_scan_clusters<<<1, 64, 0, stream>>>(clusterStart);
    km_scatter<<<NCHUNK, 256, 0, stream>>>(x, sortedC, rep, hist, clusterStart,
                                           sorted_x);
    km_fold_update<<<KC, 64, 0, stream>>>(sorted_x, clusterStart, centers);
  }
  km_sort_centers<<<1, KC, 0, stream>>>(centers, sortedC, rep);
  km_final<<<1024, 256, 0, stream>>>(x, centers, sortedC, rep, out);
}

// Round 2
// 2827.114 us; speedup vs baseline: 2.0474x; 2.0474x over previous
//
#include <hip/hip_runtime.h>
#include <stdint.h>

#define NPTS (1u << 21)   // 4*512*1024
#define KC 256
#define KM_ITERS 10
#define CHUNK 4096
#define NCHUNK (NPTS / CHUNK)   // 512

// -------- threefry2x32 (JAX PRNG) with explicit key, both output words ------
__device__ __forceinline__ uint32_t rotl32(uint32_t v, uint32_t s) {
  return (v << s) | (v >> (32u - s));
}

__device__ void threefry2x32_key(uint32_t k0, uint32_t k1,
                                 uint32_t c0, uint32_t c1,
                                 uint32_t* o0, uint32_t* o1) {
  uint32_t ks[3] = {k0, k1, k0 ^ k1 ^ 0x1BD11BDAu};
  uint32_t x0 = c0 + ks[0];
  uint32_t x1 = c1 + ks[1];
  const uint32_t rotA[4] = {13u, 15u, 26u, 6u};
  const uint32_t rotB[4] = {17u, 29u, 16u, 24u};
  #pragma unroll
  for (int i = 0; i < 5; ++i) {
    const uint32_t* rot = ((i & 1) == 0) ? rotA : rotB;
    #pragma unroll
    for (int r = 0; r < 4; ++r) {
      x0 += x1;
      x1 = rotl32(x1, rot[r]);
      x1 ^= x0;
    }
    x0 += ks[(i + 1) % 3];
    x1 += ks[(i + 2) % 3] + (uint32_t)(i + 1);
  }
  *o0 = x0;
  *o1 = x1;
}

// init: centers0 = x[randint(key(42),(256,),0,N)]  [R14/R16-validated: exact]
__global__ void km_init(const float* __restrict__ x, float* __restrict__ centers) {
  int j = threadIdx.x;  // 256 threads, 1 block
  uint32_t s0, s1;
  threefry2x32_key(0u, 42u, 0u, 1u, &s0, &s1);      // k2 = split(key(42))[1]
  uint32_t b0, b1;
  threefry2x32_key(s0, s1, 0u, (uint32_t)j, &b0, &b1);
  uint32_t idx = (b0 ^ b1) & (NPTS - 1u);
  centers[j] = x[idx];
}

// sort centers ascending (bitonic, value+orig index); rep[j] = min orig index
// among slots with equal value (exact-duplicate tie groups).
__global__ __launch_bounds__(256) void km_sort_centers(
    const float* __restrict__ centers, float* __restrict__ sortedC,
    uint32_t* __restrict__ rep) {
  __shared__ float v[KC];
  __shared__ int idx[KC];
  __shared__ uint32_t r[KC];
  const int t = threadIdx.x;
  v[t] = centers[t];
  idx[t] = t;
  __syncthreads();
  for (int size = 2; size <= KC; size <<= 1) {
    for (int stride = size >> 1; stride > 0; stride >>= 1) {
      int partner = t ^ stride;
      if (partner > t) {
        bool ascending = ((t & size) == 0);
        float va = v[t], vb = v[partner];
        int ia = idx[t], ib = idx[partner];
        bool doswap = ascending ? (va > vb) : (va < vb);
        if (doswap) { v[t] = vb; v[partner] = va; idx[t] = ib; idx[partner] = ia; }
      }
      __syncthreads();
    }
  }
  if (t == 0) {   // run-min of orig indices over equal-value groups (2 passes)
    float cv = v[0];
    uint32_t cur = (uint32_t)idx[0];
    r[0] = cur;
    for (int j = 1; j < KC; ++j) {
      if (v[j] == cv) { uint32_t ij = (uint32_t)idx[j]; cur = (ij < cur) ? ij : cur; }
      else { cv = v[j]; cur = (uint32_t)idx[j]; }
      r[j] = cur;
    }
    float nv = v[KC - 1];
    uint32_t nc = r[KC - 1];
    for (int j = KC - 2; j >= 0; --j) {
      if (v[j] == nv) { nc = (r[j] < nc) ? r[j] : nc; r[j] = nc; }
      else { nv = v[j]; nc = r[j]; }
    }
  }
  __syncthreads();
  sortedC[t] = v[t];
  rep[t] = r[t];
}

// exact-argmin via sorted binary search: upper-bound (count of <= x, capped
// 255), then 2-candidate f32 compare (same |x-c| ops as reference), ties ->
// min rep (first-original-index semantics). Exact dups handled by rep[].
__device__ __forceinline__ uint32_t bs_label(float x, const float* sC,
                                             const uint32_t* rp) {
  int pos = 0;
  #pragma unroll
  for (int d = 128; d >= 1; d >>= 1)
    if (sC[pos + d - 1] <= x) pos += d;
  if (pos == 0) return rp[0];
  float cl = sC[pos - 1], cr = sC[pos & 255];   // pos<=255 always; &255 for safety
  float dl = fabsf(x - cl), dr = fabsf(x - cr);
  if (dl < dr) return rp[pos - 1];
  if (dr < dl) return rp[pos];
  uint32_t a = rp[pos - 1], b = rp[pos];
  return a < b ? a : b;
}

// assign + per-chunk histogram via binary search (R23: replaces 256-sweep).
__global__ __launch_bounds__(256) void km_assign_hist(
    const float* __restrict__ x, const float* __restrict__ sortedC,
    const uint32_t* __restrict__ rep, uint32_t* __restrict__ hist) {
  __shared__ float sC[KC];
  __shared__ uint32_t rp[KC];
  __shared__ uint32_t sH[KC];
  const int t = threadIdx.x, b = blockIdx.x;
  sC[t] = sortedC[t];
  rp[t] = rep[t];
  sH[t] = 0u;
  __syncthreads();

  #pragma unroll
  for (int q = 0; q < 4; ++q) {
    const int i4 = b * (CHUNK / 4) + q * 256 + t;  // float4 index
    float4 xv = reinterpret_cast<const float4*>(x)[i4];
    uint32_t l0 = bs_label(xv.x, sC, rp);
    uint32_t l1 = bs_label(xv.y, sC, rp);
    uint32_t l2 = bs_label(xv.z, sC, rp);
    uint32_t l3 = bs_label(xv.w, sC, rp);
    atomicAdd(&sH[l0], 1u);
    atomicAdd(&sH[l1], 1u);
    atomicAdd(&sH[l2], 1u);
    atomicAdd(&sH[l3], 1u);
  }
  __syncthreads();
  hist[b * KC + t] = sH[t];
}

// parallel per-cluster exclusive scan over chunks (Hillis-Steele, exact ints).
__global__ __launch_bounds__(512) void km_scan_chunks(
    uint32_t* __restrict__ hist, uint32_t* __restrict__ clusterStart) {
  __shared__ uint32_t s[NCHUNK];
  const int k = blockIdx.x, t = threadIdx.x;
  uint32_t v = hist[t * KC + k];
  s[t] = v;
  __syncthreads();
  #pragma unroll
  for (int d = 1; d < NCHUNK; d <<= 1) {
    uint32_t u = (t >= d) ? s[t - d] : 0u;
    __syncthreads();
    s[t] += u;
    __syncthreads();
  }
  hist[t * KC + k] = s[t] - v;            // exclusive within cluster
  if (t == NCHUNK - 1) clusterStart[k] = s[t];  // total (temp)
}

// serial exclusive scan over the 256 cluster totals -> clusterStart[0..256]
__global__ void km_scan_clusters(uint32_t* __restrict__ clusterStart) {
  if (threadIdx.x != 0) return;
  uint32_t acc = 0;
  for (int j = 0; j < KC; ++j) {
    uint32_t t = clusterStart[j];
    clusterStart[j] = acc;
    acc += t;
  }
  clusterStart[KC] = acc;  // == NPTS
}

// stable scatter into sorted_x (= d_out used as scratch); labels via bs.
__global__ __launch_bounds__(256) void km_scatter(
    const float* __restrict__ x, const float* __restrict__ sortedC,
    const uint32_t* __restrict__ rep,
    const uint32_t* __restrict__ hist, const uint32_t* __restrict__ clusterStart,
    float* __restrict__ sorted_x) {
  __shared__ float sC[KC];
  __shared__ uint32_t rp[KC];
  __shared__ uint32_t run[KC];
  __shared__ uint32_t cntw[4][KC];
  __shared__ uint32_t basew[4][KC];
  const int t = threadIdx.x, b = blockIdx.x;
  const int w = t >> 6, lane = t & 63;
  sC[t] = sortedC[t];
  rp[t] = rep[t];
  run[t] = hist[b * KC + t] + clusterStart[t];
  __syncthreads();

  for (int r = 0; r < CHUNK / 256; ++r) {      // 16 rounds of 256 elements
    const int i = b * CHUNK + r * 256 + t;
    const float xv = x[i];
    uint32_t lab = bs_label(xv, sC, rp);
    unsigned long long m = ~0ULL;
    #pragma unroll
    for (int bit = 0; bit < 8; ++bit) {
      unsigned long long vote = __ballot((lab >> bit) & 1u);
      m &= ((lab >> bit) & 1u) ? vote : ~vote;
    }
    uint32_t rank = (uint32_t)__popcll(m & ((1ULL << lane) - 1ULL));
    uint32_t wcnt = (uint32_t)__popcll(m);
    cntw[0][t] = 0u; cntw[1][t] = 0u; cntw[2][t] = 0u; cntw[3][t] = 0u;
    __syncthreads();
    if (rank == 0) cntw[w][lab] = wcnt;
    __syncthreads();
    {
      uint32_t c0 = cntw[0][t], c1 = cntw[1][t], c2 = cntw[2][t], c3 = cntw[3][t];
      uint32_t base = run[t];
      basew[0][t] = base;
      basew[1][t] = base + c0;
      basew[2][t] = base + c0 + c1;
      basew[3][t] = base + c0 + c1 + c2;
      run[t] = base + c0 + c1 + c2 + c3;
    }
    __syncthreads();
    sorted_x[basew[w][lab] + rank] = xv;
  }
}

// ---- fold v4: coalesced lane-variant loads + readlane-fed serial chain -----
// R1 post-mortem: wave-uniform addresses got scalarized (VGPR=8, SGPR=112),
// serializing load latency onto the chain (787us). Fix: lane l vector-loads
// float4 at element 4*l of each 256-block (coalesced 1KB/wave, stays in
// VGPRs), and the bitwise-exact sequential left-fold pulls elements in index
// order via v_readlane_b32 with compile-time lane indices. Readlanes are
// independent of the chain and issue ahead; the 256-dependent-add chain
// (~1024 cyc) also covers the distance-1 prefetch of the next block.
__device__ __forceinline__ float rl_f(float v, int l) {
  return __int_as_float(__builtin_amdgcn_readlane(__float_as_int(v), l));
}

__global__ __launch_bounds__(64, 1) void km_fold_update(
    const float* __restrict__ sorted_x, const uint32_t* __restrict__ clusterStart,
    float* __restrict__ centers) {
  const int k = blockIdx.x;
  const uint32_t s0 = clusterStart[k], s1 = clusterStart[k + 1];
  const uint32_t cnt = s1 - s0;
  const float* p = sorted_x + s0;
  const uint32_t lane = threadIdx.x;
  const uint32_t nblk = cnt >> 8;   // full 256-element blocks

  float s = 0.0f;
  float4 cur, nxt;

  if (nblk > 0u) {
    cur = *reinterpret_cast<const float4*>(p + (lane << 2));
  }
  for (uint32_t t = 0u; t < nblk; ++t) {
    if (t + 1u < nblk) {
      nxt = *reinterpret_cast<const float4*>(p + (t + 1u) * 256u + (lane << 2));
    }
    #pragma unroll
    for (int l = 0; l < 64; ++l) {
      s += rl_f(cur.x, l);
      s += rl_f(cur.y, l);
      s += rl_f(cur.z, l);
      s += rl_f(cur.w, l);
    }
    cur = nxt;
  }

  // tail: remaining cnt & 255 elements, in index order (uniform scalar loads;
  // <=255 elements, latency acceptable)
  for (uint32_t j = nblk << 8; j < cnt; ++j) s += p[j];

  if (lane == 0u && cnt > 0u) centers[k] = s / (float)cnt;  // else keep old
}

// final assign + gather via binary search: out = centers[labels]
__global__ __launch_bounds__(256) void km_final(
    const float* __restrict__ x, const float* __restrict__ centers,
    const float* __restrict__ sortedC, const uint32_t* __restrict__ rep,
    float* __restrict__ out) {
  __shared__ float sC[KC];
  __shared__ uint32_t rp[KC];
  __shared__ float sCtr[KC];
  const int t = threadIdx.x;
  sC[t] = sortedC[t];
  rp[t] = rep[t];
  sCtr[t] = centers[t];
  __syncthreads();

  const int nv = (int)(NPTS / 4u);
  for (int i = blockIdx.x * blockDim.x + t; i < nv; i += gridDim.x * blockDim.x) {
    float4 xv = reinterpret_cast<const float4*>(x)[i];
    float4 o;
    o.x = sCtr[bs_label(xv.x, sC, rp)];
    o.y = sCtr[bs_label(xv.y, sC, rp)];
    o.z = sCtr[bs_label(xv.z, sC, rp)];
    o.w = sCtr[bs_label(xv.w, sC, rp)];
    reinterpret_cast<float4*>(out)[i] = o;
  }
}

extern "C" void kernel_launch(void* const* d_in, const int* in_sizes, int n_in,
                              void* d_out, int out_size, void* d_ws, size_t ws_size,
                              hipStream_t stream) {
  const float* x = (const float*)d_in[0];
  float* out = (float*)d_out;

  // ws layout (~520 KB):
  //   [0,1K)       centers f32[256]
  //   [1K,2.1K)    clusterStart u32[257]
  //   [2.5K,3.5K)  sortedC f32[256]
  //   [3.5K,4.5K)  rep u32[256]
  //   [8K,520K)    hist u32[512][256]
  // sorted_x (8 MB) lives in d_out — dead after fold, overwritten by km_final.
  uint8_t* ws = (uint8_t*)d_ws;
  float* centers = (float*)(ws + 0);
  uint32_t* clusterStart = (uint32_t*)(ws + 1024);
  float* sortedC = (float*)(ws + 2560);
  uint32_t* rep = (uint32_t*)(ws + 3584);
  uint32_t* hist = (uint32_t*)(ws + 8192);
  float* sorted_x = (float*)d_out;

  km_init<<<1, KC, 0, stream>>>(x, centers);
  for (int it = 0; it < KM_ITERS; ++it) {
    km_sort_centers<<<1, KC, 0, stream>>>(centers, sortedC, rep);
    km_assign_hist<<<NCHUNK, 256, 0, stream>>>(x, sortedC, rep, hist);
    km_scan_chunks<<<KC, NCHUNK, 0, stream>>>(hist, clusterStart);
    km_scan_clusters<<<1, 64, 0, stream>>>(clusterStart);
    km_scatter<<<NCHUNK, 256, 0, stream>>>(x, sortedC, rep, hist, clusterStart,
                                           sorted_x);
    km_fold_update<<<KC, 64, 0, stream>>>(sorted_x, clusterStart, centers);
  }
  km_sort_centers<<<1, KC, 0, stream>>>(centers, sortedC, rep);
  km_final<<<1024, 256, 0, stream>>>(x, centers, sortedC, rep, out);
}

// Round 3
// 1898.477 us; speedup vs baseline: 3.0489x; 1.4891x over previous
//
#include <hip/hip_runtime.h>
#include <stdint.h>

#define NPTS (1u << 21)   // 4*512*1024
#define KC 256
#define KM_ITERS 10
#define CHUNK 4096
#define NCHUNK (NPTS / CHUNK)   // 512

// -------- threefry2x32 (JAX PRNG) with explicit key, both output words ------
__device__ __forceinline__ uint32_t rotl32(uint32_t v, uint32_t s) {
  return (v << s) | (v >> (32u - s));
}

__device__ void threefry2x32_key(uint32_t k0, uint32_t k1,
                                 uint32_t c0, uint32_t c1,
                                 uint32_t* o0, uint32_t* o1) {
  uint32_t ks[3] = {k0, k1, k0 ^ k1 ^ 0x1BD11BDAu};
  uint32_t x0 = c0 + ks[0];
  uint32_t x1 = c1 + ks[1];
  const uint32_t rotA[4] = {13u, 15u, 26u, 6u};
  const uint32_t rotB[4] = {17u, 29u, 16u, 24u};
  #pragma unroll
  for (int i = 0; i < 5; ++i) {
    const uint32_t* rot = ((i & 1) == 0) ? rotA : rotB;
    #pragma unroll
    for (int r = 0; r < 4; ++r) {
      x0 += x1;
      x1 = rotl32(x1, rot[r]);
      x1 ^= x0;
    }
    x0 += ks[(i + 1) % 3];
    x1 += ks[(i + 2) % 3] + (uint32_t)(i + 1);
  }
  *o0 = x0;
  *o1 = x1;
}

// init: centers0 = x[randint(key(42),(256,),0,N)]  [R14/R16-validated: exact]
__global__ void km_init(const float* __restrict__ x, float* __restrict__ centers) {
  int j = threadIdx.x;  // 256 threads, 1 block
  uint32_t s0, s1;
  threefry2x32_key(0u, 42u, 0u, 1u, &s0, &s1);      // k2 = split(key(42))[1]
  uint32_t b0, b1;
  threefry2x32_key(s0, s1, 0u, (uint32_t)j, &b0, &b1);
  uint32_t idx = (b0 ^ b1) & (NPTS - 1u);
  centers[j] = x[idx];
}

// sort centers ascending (bitonic, value+orig index); rep[j] = min orig index
// among slots with equal value (exact-duplicate tie groups).
__global__ __launch_bounds__(256) void km_sort_centers(
    const float* __restrict__ centers, float* __restrict__ sortedC,
    uint32_t* __restrict__ rep) {
  __shared__ float v[KC];
  __shared__ int idx[KC];
  __shared__ uint32_t r[KC];
  const int t = threadIdx.x;
  v[t] = centers[t];
  idx[t] = t;
  __syncthreads();
  for (int size = 2; size <= KC; size <<= 1) {
    for (int stride = size >> 1; stride > 0; stride >>= 1) {
      int partner = t ^ stride;
      if (partner > t) {
        bool ascending = ((t & size) == 0);
        float va = v[t], vb = v[partner];
        int ia = idx[t], ib = idx[partner];
        bool doswap = ascending ? (va > vb) : (va < vb);
        if (doswap) { v[t] = vb; v[partner] = va; idx[t] = ib; idx[partner] = ia; }
      }
      __syncthreads();
    }
  }
  if (t == 0) {   // run-min of orig indices over equal-value groups (2 passes)
    float cv = v[0];
    uint32_t cur = (uint32_t)idx[0];
    r[0] = cur;
    for (int j = 1; j < KC; ++j) {
      if (v[j] == cv) { uint32_t ij = (uint32_t)idx[j]; cur = (ij < cur) ? ij : cur; }
      else { cv = v[j]; cur = (uint32_t)idx[j]; }
      r[j] = cur;
    }
    float nv = v[KC - 1];
    uint32_t nc = r[KC - 1];
    for (int j = KC - 2; j >= 0; --j) {
      if (v[j] == nv) { nc = (r[j] < nc) ? r[j] : nc; r[j] = nc; }
      else { nv = v[j]; nc = r[j]; }
    }
  }
  __syncthreads();
  sortedC[t] = v[t];
  rep[t] = r[t];
}

// exact-argmin via sorted binary search: upper-bound (count of <= x, capped
// 255), then 2-candidate f32 compare (same |x-c| ops as reference), ties ->
// min rep (first-original-index semantics). Exact dups handled by rep[].
__device__ __forceinline__ uint32_t bs_label(float x, const float* sC,
                                             const uint32_t* rp) {
  int pos = 0;
  #pragma unroll
  for (int d = 128; d >= 1; d >>= 1)
    if (sC[pos + d - 1] <= x) pos += d;
  if (pos == 0) return rp[0];
  float cl = sC[pos - 1], cr = sC[pos & 255];   // pos<=255 always; &255 for safety
  float dl = fabsf(x - cl), dr = fabsf(x - cr);
  if (dl < dr) return rp[pos - 1];
  if (dr < dl) return rp[pos];
  uint32_t a = rp[pos - 1], b = rp[pos];
  return a < b ? a : b;
}

// assign + per-chunk histogram via binary search (R23: replaces 256-sweep).
__global__ __launch_bounds__(256) void km_assign_hist(
    const float* __restrict__ x, const float* __restrict__ sortedC,
    const uint32_t* __restrict__ rep, uint32_t* __restrict__ hist) {
  __shared__ float sC[KC];
  __shared__ uint32_t rp[KC];
  __shared__ uint32_t sH[KC];
  const int t = threadIdx.x, b = blockIdx.x;
  sC[t] = sortedC[t];
  rp[t] = rep[t];
  sH[t] = 0u;
  __syncthreads();

  #pragma unroll
  for (int q = 0; q < 4; ++q) {
    const int i4 = b * (CHUNK / 4) + q * 256 + t;  // float4 index
    float4 xv = reinterpret_cast<const float4*>(x)[i4];
    uint32_t l0 = bs_label(xv.x, sC, rp);
    uint32_t l1 = bs_label(xv.y, sC, rp);
    uint32_t l2 = bs_label(xv.z, sC, rp);
    uint32_t l3 = bs_label(xv.w, sC, rp);
    atomicAdd(&sH[l0], 1u);
    atomicAdd(&sH[l1], 1u);
    atomicAdd(&sH[l2], 1u);
    atomicAdd(&sH[l3], 1u);
  }
  __syncthreads();
  hist[b * KC + t] = sH[t];
}

// parallel per-cluster exclusive scan over chunks (Hillis-Steele, exact ints).
__global__ __launch_bounds__(512) void km_scan_chunks(
    uint32_t* __restrict__ hist, uint32_t* __restrict__ clusterStart) {
  __shared__ uint32_t s[NCHUNK];
  const int k = blockIdx.x, t = threadIdx.x;
  uint32_t v = hist[t * KC + k];
  s[t] = v;
  __syncthreads();
  #pragma unroll
  for (int d = 1; d < NCHUNK; d <<= 1) {
    uint32_t u = (t >= d) ? s[t - d] : 0u;
    __syncthreads();
    s[t] += u;
    __syncthreads();
  }
  hist[t * KC + k] = s[t] - v;            // exclusive within cluster
  if (t == NCHUNK - 1) clusterStart[k] = s[t];  // total (temp)
}

// serial exclusive scan over the 256 cluster totals -> clusterStart[0..256]
__global__ void km_scan_clusters(uint32_t* __restrict__ clusterStart) {
  if (threadIdx.x != 0) return;
  uint32_t acc = 0;
  for (int j = 0; j < KC; ++j) {
    uint32_t t = clusterStart[j];
    clusterStart[j] = acc;
    acc += t;
  }
  clusterStart[KC] = acc;  // == NPTS
}

// stable scatter into sorted_x (= d_out used as scratch); labels via bs.
__global__ __launch_bounds__(256) void km_scatter(
    const float* __restrict__ x, const float* __restrict__ sortedC,
    const uint32_t* __restrict__ rep,
    const uint32_t* __restrict__ hist, const uint32_t* __restrict__ clusterStart,
    float* __restrict__ sorted_x) {
  __shared__ float sC[KC];
  __shared__ uint32_t rp[KC];
  __shared__ uint32_t run[KC];
  __shared__ uint32_t cntw[4][KC];
  __shared__ uint32_t basew[4][KC];
  const int t = threadIdx.x, b = blockIdx.x;
  const int w = t >> 6, lane = t & 63;
  sC[t] = sortedC[t];
  rp[t] = rep[t];
  run[t] = hist[b * KC + t] + clusterStart[t];
  __syncthreads();

  for (int r = 0; r < CHUNK / 256; ++r) {      // 16 rounds of 256 elements
    const int i = b * CHUNK + r * 256 + t;
    const float xv = x[i];
    uint32_t lab = bs_label(xv, sC, rp);
    unsigned long long m = ~0ULL;
    #pragma unroll
    for (int bit = 0; bit < 8; ++bit) {
      unsigned long long vote = __ballot((lab >> bit) & 1u);
      m &= ((lab >> bit) & 1u) ? vote : ~vote;
    }
    uint32_t rank = (uint32_t)__popcll(m & ((1ULL << lane) - 1ULL));
    uint32_t wcnt = (uint32_t)__popcll(m);
    cntw[0][t] = 0u; cntw[1][t] = 0u; cntw[2][t] = 0u; cntw[3][t] = 0u;
    __syncthreads();
    if (rank == 0) cntw[w][lab] = wcnt;
    __syncthreads();
    {
      uint32_t c0 = cntw[0][t], c1 = cntw[1][t], c2 = cntw[2][t], c3 = cntw[3][t];
      uint32_t base = run[t];
      basew[0][t] = base;
      basew[1][t] = base + c0;
      basew[2][t] = base + c0 + c1;
      basew[3][t] = base + c0 + c1 + c2;
      run[t] = base + c0 + c1 + c2 + c3;
    }
    __syncthreads();
    sorted_x[basew[w][lab] + rank] = xv;
  }
}

// ---- fold v5: single-wave LDS ring, distance-3 group pipeline --------------
// R1/R2 lesson: global/readlane feeds get scalarized or SGPR-hazard-stalled;
// LDS feeds are scalarization-proof (no scalar LDS pipe). Structure:
//  - 1 wave/block, NO barriers (single instruction stream, program order).
//  - 4-tile ring (4x256 floats); all lanes stage tile t+2/t+3 via coalesced
//    float4 global loads (lane-variant, clamped to NPTS-4) + ds_write.
//  - lane 0 folds with 4 register sets of 8 float4: reads for group g+3
//    issued before folding group g (384 chain-cyc cover vs ~220 cyc read
//    completion -> no lgkm stalls).
// Fold order bitwise-identical to validated left-fold (tiles asc, groups asc,
// float4s asc, .x.y.z.w).
#define F4A(q) s += (q).x; s += (q).y; s += (q).z; s += (q).w;

#define LOAD_GRP(S, g) { uint32_t b_ = (((g) & 31u) << 3); \
  S##0 = r4[b_ + 0]; S##1 = r4[b_ + 1]; S##2 = r4[b_ + 2]; S##3 = r4[b_ + 3]; \
  S##4 = r4[b_ + 4]; S##5 = r4[b_ + 5]; S##6 = r4[b_ + 6]; S##7 = r4[b_ + 7]; }

#define FOLD_GRP(S) { F4A(S##0) F4A(S##1) F4A(S##2) F4A(S##3) \
                      F4A(S##4) F4A(S##5) F4A(S##6) F4A(S##7) }

#define FOLD_TILE(tt) { uint32_t gb_ = ((uint32_t)(tt)) << 3; \
  LOAD_GRP(q3, gb_ + 3u)  FOLD_GRP(q0) \
  LOAD_GRP(q0, gb_ + 4u)  FOLD_GRP(q1) \
  LOAD_GRP(q1, gb_ + 5u)  FOLD_GRP(q2) \
  LOAD_GRP(q2, gb_ + 6u)  FOLD_GRP(q3) \
  LOAD_GRP(q3, gb_ + 7u)  FOLD_GRP(q0) \
  LOAD_GRP(q0, gb_ + 8u)  FOLD_GRP(q1) \
  LOAD_GRP(q1, gb_ + 9u)  FOLD_GRP(q2) \
  LOAD_GRP(q2, gb_ + 10u) FOLD_GRP(q3) }

__global__ __launch_bounds__(64, 1) void km_fold_update(
    const float* __restrict__ sorted_x, const uint32_t* __restrict__ clusterStart,
    float* __restrict__ centers) {
  __shared__ __align__(16) float ring[1024];   // 4 tiles x 256 floats
  const int k = blockIdx.x;
  const uint32_t s0 = clusterStart[k], s1 = clusterStart[k + 1];
  const uint32_t cnt = s1 - s0;
  if (cnt == 0u) return;                        // keep old center
  const uint32_t lane = threadIdx.x;
  const uint32_t nfull = cnt >> 8;              // full 256-elem tiles
  const uint32_t m = cnt & 255u;                // partial remainder

  float4* w4 = reinterpret_cast<float4*>(ring);
  const float4* r4 = reinterpret_cast<const float4*>(ring);

  // clamped, coalesced, lane-variant global float4 load of tile t
  auto glo = [&](uint32_t t) -> float4 {
    uint32_t e = s0 + (t << 8) + (lane << 2);
    e = (e > (NPTS - 4u)) ? (NPTS - 4u) : e;
    return *reinterpret_cast<const float4*>(sorted_x + e);
  };

  // prologue: stage tiles 0,1; leave loads of tiles 2,3 in flight
  float4 rvA = glo(0u), rvB = glo(1u);
  w4[(0u << 6) + lane] = rvA;
  w4[(1u << 6) + lane] = rvB;
  rvA = glo(2u);
  rvB = glo(3u);

  float s = 0.0f;
  float4 q00, q01, q02, q03, q04, q05, q06, q07;
  float4 q10, q11, q12, q13, q14, q15, q16, q17;
  float4 q20, q21, q22, q23, q24, q25, q26, q27;
  float4 q30, q31, q32, q33, q34, q35, q36, q37;
  #define q0 q0
  #undef q0

  if (lane == 0u) {       // pre-load groups 0..2 into sets 0..2
    LOAD_GRP(q0, 0u)
    LOAD_GRP(q1, 1u)
    LOAD_GRP(q2, 2u)
  }

  uint32_t t = 0u;
  for (; t + 1u < nfull; t += 2u) {
    if (lane == 0u) { FOLD_TILE(t) }
    w4[(((t + 2u) & 3u) << 6) + lane] = rvA;
    rvA = glo(t + 4u);
    if (lane == 0u) { FOLD_TILE(t + 1u) }
    w4[(((t + 3u) & 3u) << 6) + lane] = rvB;
    rvB = glo(t + 5u);
  }
  if (t < nfull) {                 // leftover full tile (odd nfull / nfull==1)
    if (lane == 0u) { FOLD_TILE(t) }
  }

  if (lane == 0u) {
    if (m) {                       // partial tile, staged in ring slot nfull&3
      const float* bb = ring + ((nfull & 3u) << 8);
      uint32_t j = 0;
      for (; j + 16u <= m; j += 16u) {
        float v0 = bb[j + 0], v1 = bb[j + 1], v2 = bb[j + 2], v3 = bb[j + 3];
        float v4 = bb[j + 4], v5 = bb[j + 5], v6 = bb[j + 6], v7 = bb[j + 7];
        float v8 = bb[j + 8], v9 = bb[j + 9], va = bb[j + 10], vb = bb[j + 11];
        float vc = bb[j + 12], vd = bb[j + 13], ve = bb[j + 14], vf = bb[j + 15];
        s += v0; s += v1; s += v2; s += v3;
        s += v4; s += v5; s += v6; s += v7;
        s += v8; s += v9; s += va; s += vb;
        s += vc; s += vd; s += ve; s += vf;
      }
      for (; j < m; ++j) s += bb[j];
    }
    centers[k] = s / (float)cnt;
  }
}

// naming shim used above (sets are q0x..q3x)
#define q00_UNUSED 0
// (LOAD_GRP/FOLD_GRP reference S##0..S##7; q0 -> q00..q07 etc. via tokens
//  q0,q1,q2,q3 -- the concatenation below makes q0##0 == q00.)

// final assign + gather via binary search: out = centers[labels]
__global__ __launch_bounds__(256) void km_final(
    const float* __restrict__ x, const float* __restrict__ centers,
    const float* __restrict__ sortedC, const uint32_t* __restrict__ rep,
    float* __restrict__ out) {
  __shared__ float sC[KC];
  __shared__ uint32_t rp[KC];
  __shared__ float sCtr[KC];
  const int t = threadIdx.x;
  sC[t] = sortedC[t];
  rp[t] = rep[t];
  sCtr[t] = centers[t];
  __syncthreads();

  const int nv = (int)(NPTS / 4u);
  for (int i = blockIdx.x * blockDim.x + t; i < nv; i += gridDim.x * blockDim.x) {
    float4 xv = reinterpret_cast<const float4*>(x)[i];
    float4 o;
    o.x = sCtr[bs_label(xv.x, sC, rp)];
    o.y = sCtr[bs_label(xv.y, sC, rp)];
    o.z = sCtr[bs_label(xv.z, sC, rp)];
    o.w = sCtr[bs_label(xv.w, sC, rp)];
    reinterpret_cast<float4*>(out)[i] = o;
  }
}

extern "C" void kernel_launch(void* const* d_in, const int* in_sizes, int n_in,
                              void* d_out, int out_size, void* d_ws, size_t ws_size,
                              hipStream_t stream) {
  const float* x = (const float*)d_in[0];
  float* out = (float*)d_out;

  // ws layout (~520 KB):
  //   [0,1K)       centers f32[256]
  //   [1K,2.1K)    clusterStart u32[257]
  //   [2.5K,3.5K)  sortedC f32[256]
  //   [3.5K,4.5K)  rep u32[256]
  //   [8K,520K)    hist u32[512][256]
  // sorted_x (8 MB) lives in d_out — dead after fold, overwritten by km_final.
  uint8_t* ws = (uint8_t*)d_ws;
  float* centers = (float*)(ws + 0);
  uint32_t* clusterStart = (uint32_t*)(ws + 1024);
  float* sortedC = (float*)(ws + 2560);
  uint32_t* rep = (uint32_t*)(ws + 3584);
  uint32_t* hist = (uint32_t*)(ws + 8192);
  float* sorted_x = (float*)d_out;

  km_init<<<1, KC, 0, stream>>>(x, centers);
  for (int it = 0; it < KM_ITERS; ++it) {
    km_sort_centers<<<1, KC, 0, stream>>>(centers, sortedC, rep);
    km_assign_hist<<<NCHUNK, 256, 0, stream>>>(x, sortedC, rep, hist);
    km_scan_chunks<<<KC, NCHUNK, 0, stream>>>(hist, clusterStart);
    km_scan_clusters<<<1, 64, 0, stream>>>(clusterStart);
    km_scatter<<<NCHUNK, 256, 0, stream>>>(x, sortedC, rep, hist, clusterStart,
                                           sorted_x);
    km_fold_update<<<KC, 64, 0, stream>>>(sorted_x, clusterStart, centers);
  }
  km_sort_centers<<<1, KC, 0, stream>>>(centers, sortedC, rep);
  km_final<<<1024, 256, 0, stream>>>(x, centers, sortedC, rep, out);
}